// Round 6
// baseline (3120.545 us; speedup 1.0000x reference)
//
#include <hip/hip_runtime.h>
#include <hip/hip_bf16.h>

#define NN 4096    // nodes == feature dim
#define NE 32768   // edges
#define NEMB 8

typedef __bf16 bf16x8 __attribute__((ext_vector_type(8)));
typedef float  f32x4  __attribute__((ext_vector_type(4)));

__device__ __forceinline__ unsigned short f2bf(float f) {
  union { float f; unsigned int u; } v; v.f = f;
  return (unsigned short)((v.u + 0x7FFFu + ((v.u >> 16) & 1u)) >> 16);
}

// ---------------- f32 -> bf16 bulk convert ----------------
__global__ void k_f2bf(const float* __restrict__ in, unsigned short* __restrict__ out, long n8) {
  long i = (long)blockIdx.x * blockDim.x + threadIdx.x;
  long stride = (long)gridDim.x * blockDim.x;
  for (long j = i; j < n8; j += stride) {
    const float* p = in + j * 8;
    float4 a = *(const float4*)p;
    float4 b = *(const float4*)(p + 4);
    union { unsigned short u[8]; uint4 v; } o;
    o.u[0] = f2bf(a.x); o.u[1] = f2bf(a.y); o.u[2] = f2bf(a.z); o.u[3] = f2bf(a.w);
    o.u[4] = f2bf(b.x); o.u[5] = f2bf(b.y); o.u[6] = f2bf(b.z); o.u[7] = f2bf(b.w);
    *(uint4*)(out + j * 8) = o.v;
  }
}

// ---------------- graph prep ----------------
__global__ void k_deg_init(float* deg) { deg[blockIdx.x * 256 + threadIdx.x] = 1.0f; }

__global__ void k_edge_accum(const int* __restrict__ ei, const float* __restrict__ ew,
                             float* deg, int* cnt) {
  int e = blockIdx.x * 256 + threadIdx.x;
  if (e >= NE) return;
  int c = ei[NE + e];
  atomicAdd(&deg[c], ew[e]);
  atomicAdd(&cnt[c], 1);
}

__global__ void k_dis(const float* __restrict__ deg, float* __restrict__ dis) {
  int i = blockIdx.x * 256 + threadIdx.x;
  float d = deg[i];
  dis[i] = d > 0.f ? rsqrtf(d) : 0.f;
}

__global__ void k_scan(const int* __restrict__ cnt, int* __restrict__ starts) {
  __shared__ int sh[1024];
  int tid = threadIdx.x;
  int base = tid * 4;
  int v[4]; int sum = 0;
  for (int i = 0; i < 4; i++) { v[i] = cnt[base + i]; sum += v[i]; }
  sh[tid] = sum;
  __syncthreads();
  for (int offd = 1; offd < 1024; offd <<= 1) {
    int t = (tid >= offd) ? sh[tid - offd] : 0;
    __syncthreads();
    sh[tid] += t;
    __syncthreads();
  }
  int run = sh[tid] - sum;
  for (int i = 0; i < 4; i++) { starts[base + i] = run; run += v[i]; }
}

__global__ void k_fill(const int* __restrict__ ei, const int* __restrict__ starts,
                       int* cursor, int* csr_e) {
  int e = blockIdx.x * 256 + threadIdx.x;
  if (e >= NE) return;
  int c = ei[NE + e];
  int pos = atomicAdd(&cursor[c], 1);
  csr_e[starts[c] + pos] = e;
}

__global__ void k_sortnorm(const int* __restrict__ ei, const float* __restrict__ ew,
                           const int* __restrict__ starts, const int* __restrict__ cnt,
                           const float* __restrict__ dis,
                           int* csr_e, int* __restrict__ csr_row, float* __restrict__ csr_nrm) {
  int n = blockIdx.x * 256 + threadIdx.x;
  if (n >= NN) return;
  int s = starts[n], c = cnt[n];
  for (int i = 1; i < c; i++) {
    int key = csr_e[s + i]; int j = i - 1;
    while (j >= 0 && csr_e[s + j] > key) { csr_e[s + j + 1] = csr_e[s + j]; j--; }
    csr_e[s + j + 1] = key;
  }
  float dn = dis[n];
  for (int i = 0; i < c; i++) {
    int e = csr_e[s + i];
    int r = ei[e];
    csr_row[s + i] = r;
    csr_nrm[s + i] = dis[r] * ew[e] * dn;
  }
}

// ---------------- aggregate + tanh -> H1 (bf16) ----------------
__global__ __launch_bounds__(256) void k_agg(
    const float* __restrict__ h, const float* __restrict__ dis,
    const int* __restrict__ starts, const int* __restrict__ cnt,
    const int* __restrict__ csr_row, const float* __restrict__ csr_nrm,
    const float* __restrict__ gcn_b, unsigned short* __restrict__ H1b) {
  int n = blockIdx.x;
  int tid = threadIdx.x;
  float dn = dis[n];
  float sw = dn * dn;
  float acc[16];
  const float* hn = h + (size_t)n * NN;
  #pragma unroll
  for (int i = 0; i < 16; i++) { int f = tid + i * 256; acc[i] = sw * hn[f] + gcn_b[f]; }
  int s = starts[n], c = cnt[n];
  __shared__ int   s_row[64];
  __shared__ float s_nrm[64];
  for (int base = 0; base < c; base += 64) {
    int m = min(64, c - base);
    __syncthreads();
    if (tid < m) { s_row[tid] = csr_row[s + base + tid]; s_nrm[tid] = csr_nrm[s + base + tid]; }
    __syncthreads();
    for (int j = 0; j < m; j++) {
      const float* hr = h + (size_t)s_row[j] * NN;
      float wgt = s_nrm[j];
      #pragma unroll
      for (int i = 0; i < 16; i++) acc[i] += wgt * hr[tid + i * 256];
    }
  }
  #pragma unroll
  for (int i = 0; i < 16; i++)
    H1b[(size_t)n * NN + tid + i * 256] = f2bf(tanhf(acc[i]));
}

// ---------------- 8-phase 256x256 MFMA GEMM, reg-pipelined ds_reads ----------------
__device__ __forceinline__ void gload16(const void* g, void* l) {
  __builtin_amdgcn_global_load_lds(
      (const __attribute__((address_space(1))) unsigned int*)g,
      (__attribute__((address_space(3))) unsigned int*)l, 16, 0, 0);
}

#define BARX() do { __builtin_amdgcn_sched_barrier(0); __builtin_amdgcn_s_barrier(); __builtin_amdgcn_sched_barrier(0); } while (0)
#define LGKM(n) do { asm volatile("s_waitcnt lgkmcnt(" #n ")" ::: "memory"); __builtin_amdgcn_sched_barrier(0); } while (0)
#define VMC(n) do { asm volatile("s_waitcnt vmcnt(" #n ")" ::: "memory"); } while (0)

// LDS: [buf][A/B][kk][frag 0..15][64 slots x 8 shorts] (16-B slots).
// Producer (gload_lds, linear dest): lane l = 4q+j stages
//   M[frag*16 + q][k-chunk j ^ ((q>>1)&3)]  -> quad = same row, 64-B segment (coalesced).
// Consumer: lane λ (row r=λ&15, chunk c=λ>>4) reads slot 4r + (c ^ ((r>>1)&3)).
// Every 8-lane group hits slots ≡ {0,4,1,5,2,6,3,7} mod 8 -> zero bank conflicts.
//
// SCHEDULE (reg-pipelined): phase p's pre-window issues the ds_reads for phase
// p+1 into the alternate register set; the counted lgkm wait at p retires only
// phase p-1's reads (which completed under p-1's MFMA window). vmcnt waits sit
// at odd-phase ends BEFORE the trailing barrier, so every wave retires its own
// stage chunk before any wave crosses the barrier and reads it (per-wave vmcnt).

#define STAGE(buf, mat, kk, tk) do { \
    size_t off_ = (size_t)(tk) * 64 + (kk) * 32; \
    gload16((mat ? gB0 : gA0) + off_, &LDS[buf][mat][kk][c0][0]); \
    gload16((mat ? gB1 : gA1) + off_, &LDS[buf][mat][kk][c0 + 1][0]); \
  } while (0)

#define LDA4(dst, buf, kk, q) do { \
    const unsigned short* b_ = &LDS[buf][0][kk][wr * 8 + (q) * 4][0] + aoff; \
    dst[0] = *(const bf16x8*)(b_); \
    dst[1] = *(const bf16x8*)(b_ + 512); \
    dst[2] = *(const bf16x8*)(b_ + 1024); \
    dst[3] = *(const bf16x8*)(b_ + 1536); \
  } while (0)

#define LDB4(dst, buf, kk) do { \
    const unsigned short* b_ = &LDS[buf][1][kk][wc * 4][0] + aoff; \
    dst[0] = *(const bf16x8*)(b_); \
    dst[1] = *(const bf16x8*)(b_ + 512); \
    dst[2] = *(const bf16x8*)(b_ + 1024); \
    dst[3] = *(const bf16x8*)(b_ + 1536); \
  } while (0)

#define MMA16(q, av, bv) do { \
    __builtin_amdgcn_s_setprio(1); \
    _Pragma("unroll") \
    for (int mf_ = 0; mf_ < 4; mf_++) \
      _Pragma("unroll") \
      for (int nf_ = 0; nf_ < 4; nf_++) \
        acc[(q) * 4 + mf_][nf_] = __builtin_amdgcn_mfma_f32_16x16x32_bf16(av[mf_], bv[nf_], acc[(q) * 4 + mf_][nf_], 0, 0, 0); \
    __builtin_amdgcn_s_setprio(0); \
  } while (0)

template<bool FUSED>
__global__ __launch_bounds__(512, 2) void gemm8(
    const unsigned short* __restrict__ A,  // [M][K] bf16
    const unsigned short* __restrict__ B,  // [N][K] bf16
    int N, int K, int nRb,
    float* __restrict__ outF,
    const float* __restrict__ colBias,
    const float* __restrict__ rowW,
    float* __restrict__ P) {
  __shared__ unsigned short LDS[2][2][2][16][512];  // 128 KiB

  const int nwg = gridDim.x, n8 = nwg >> 3;
  const int bid = blockIdx.x;
  const int swz = (bid & 7) * n8 + (bid >> 3);   // XCD-aware, bijective (nwg % 8 == 0)
  const int rb = swz % nRb, cb = swz / nRb;
  const int row0 = rb * 256, col0 = cb * 256;

  const int tid = threadIdx.x;
  const int w = tid >> 6, l = tid & 63;
  const int wr = w >> 2, wc = w & 3;             // 2M x 4N wave grid
  const int l15 = l & 15, kl = l >> 4;

  // producer gather: wave w owns frags c0, c0+1; lane l = 4q+j
  const int c0 = w * 2;
  const int pq = l >> 2;                          // row within 16-row frag
  const int pc = (l & 3) ^ ((l >> 3) & 3);        // XOR-permuted k-chunk (16 B units)
  const unsigned short* gA0 = A + (size_t)(row0 + c0 * 16 + pq) * K + pc * 8;
  const unsigned short* gA1 = gA0 + (size_t)16 * K;
  const unsigned short* gB0 = B + (size_t)(col0 + c0 * 16 + pq) * K + pc * 8;
  const unsigned short* gB1 = gB0 + (size_t)16 * K;

  // consumer read offset within a frag block (shorts): slot 4r + (c ^ ((r>>1)&3))
  const int aoff = l15 * 32 + ((kl ^ ((l >> 1) & 3)) << 3);

  f32x4 acc[8][4];
  #pragma unroll
  for (int m = 0; m < 8; m++)
    #pragma unroll
    for (int n = 0; n < 4; n++)
      acc[m][n] = f32x4{0.f, 0.f, 0.f, 0.f};

  bf16x8 avA[4], avB[4], bvA[4], bvB[4];

  // prologue: tile0 fully + tile1 kk0; then preload ph1 fragments
  STAGE(0, 0, 0, 0); STAGE(0, 1, 0, 0); STAGE(0, 0, 1, 0); STAGE(0, 1, 1, 0);
  STAGE(1, 0, 0, 1); STAGE(1, 1, 0, 1);
  VMC(4);
  BARX();
  LDB4(bvA, 0, 0); LDA4(avA, 0, 0, 0);

  const int NIT = K >> 7;   // 2 K-tiles (BK=64) per iteration
  for (int i = 0; i < NIT; i++) {
    const int ta = 2 * i, tb = 2 * i + 1;
    const bool mid = (i < NIT - 1);
    // ph1: MFMA(buf0,kk0,q0) | early: av(buf0,kk0,q1) | stage A-kk1(tb)
    LDA4(avB, 0, 0, 1);
    STAGE(1, 0, 1, tb);
    BARX(); LGKM(4); MMA16(0, avA, bvA); VMC(6); BARX();
    // ph2: MFMA(buf0,kk0,q1) | early: bv+av(buf0,kk1,q0) | stage B-kk1(tb)
    LDB4(bvB, 0, 1); LDA4(avA, 0, 1, 0);
    STAGE(1, 1, 1, tb);
    BARX(); LGKM(8); MMA16(1, avB, bvA); BARX();
    // ph3: MFMA(buf0,kk1,q0) | early: av(buf0,kk1,q1) | stage A-kk0(ta+2)
    LDA4(avB, 0, 1, 1);
    if (mid) STAGE(0, 0, 0, ta + 2);
    BARX(); LGKM(4); MMA16(0, avA, bvB);
    if (mid) VMC(6); else VMC(4);
    BARX();
    // ph4: MFMA(buf0,kk1,q1) | early: bv+av(buf1,kk0,q0) | stage B-kk0(ta+2)
    LDB4(bvA, 1, 0); LDA4(avA, 1, 0, 0);
    if (mid) STAGE(0, 1, 0, ta + 2);
    BARX(); LGKM(8); MMA16(1, avB, bvB); BARX();
    // ph5: MFMA(buf1,kk0,q0) | early: av(buf1,kk0,q1) | stage A-kk1(ta+2)
    LDA4(avB, 1, 0, 1);
    if (mid) STAGE(0, 0, 1, ta + 2);
    BARX(); LGKM(4); MMA16(0, avA, bvA);
    if (mid) VMC(6); else VMC(0);
    BARX();
    // ph6: MFMA(buf1,kk0,q1) | early: bv+av(buf1,kk1,q0) | stage B-kk1(ta+2)
    LDB4(bvB, 1, 1); LDA4(avA, 1, 1, 0);
    if (mid) STAGE(0, 1, 1, ta + 2);
    BARX(); LGKM(8); MMA16(1, avB, bvA); BARX();
    // ph7: MFMA(buf1,kk1,q0) | early: av(buf1,kk1,q1) | stage A-kk0(tb+2)
    LDA4(avB, 1, 1, 1);
    if (mid) STAGE(1, 0, 0, tb + 2);
    BARX(); LGKM(4); MMA16(0, avA, bvB); VMC(6); BARX();
    // ph8: MFMA(buf1,kk1,q1) | early: bv+av(next buf0,kk0,q0) | stage B-kk0(tb+2)
    if (mid) {
      LDB4(bvA, 0, 0); LDA4(avA, 0, 0, 0);
      STAGE(1, 1, 0, tb + 2);
      BARX(); LGKM(8); MMA16(1, avB, bvB); BARX();
    } else {
      BARX(); LGKM(0); MMA16(1, avB, bvB); BARX();
    }
  }

  if (!FUSED) {
    #pragma unroll
    for (int mf = 0; mf < 8; mf++)
      #pragma unroll
      for (int nf = 0; nf < 4; nf++) {
        int row = row0 + wr * 128 + mf * 16 + kl * 4;
        int col = col0 + wc * 64 + nf * 16 + l15;
        float* o = outF + (size_t)row * N + col;
        #pragma unroll
        for (int r = 0; r < 4; r++) o[(size_t)r * N] = acc[mf][nf][r];
      }
  } else {
    #pragma unroll
    for (int nf = 0; nf < 4; nf++) {
      int col = col0 + wc * 64 + nf * 16 + l15;
      float bias = colBias[col];
      float s = 0.f;
      #pragma unroll
      for (int mf = 0; mf < 8; mf++) {
        int rbase = row0 + wr * 128 + mf * 16 + kl * 4;
        #pragma unroll
        for (int r = 0; r < 4; r++)
          s += rowW[rbase + r] * tanhf(acc[mf][nf][r] + bias);
      }
      s += __shfl_xor(s, 16, 64);
      s += __shfl_xor(s, 32, 64);
      if (l < 16) P[(size_t)(rb * 2 + wr) * N + col] = s;
    }
  }
}

// ---------------- final deterministic reduction ----------------
__global__ void k_final(const float* __restrict__ P, const float* __restrict__ emb,
                        const float* __restrict__ wf, const float* __restrict__ wfb,
                        float* __restrict__ out) {
  int e = blockIdx.x * 256 + threadIdx.x;
  float s = 0.f;
  for (int r = 0; r < 32; r++) s += P[(size_t)r * NE + e];
  float c = wfb[0];
  #pragma unroll
  for (int k = 0; k < NEMB; k++) c += emb[e * NEMB + k] * wf[NN + k];
  out[e] = s + c;
}

extern "C" void kernel_launch(void* const* d_in, const int* in_sizes, int n_in,
                              void* d_out, int out_size, void* d_ws, size_t ws_size,
                              hipStream_t stream) {
  const float* x    = (const float*)d_in[0];
  const int*   ei   = (const int*)d_in[1];
  const float* ew   = (const float*)d_in[2];
  const float* gcnw = (const float*)d_in[3];
  const float* gcnb = (const float*)d_in[4];
  const float* wqw  = (const float*)d_in[5];
  const float* wqb  = (const float*)d_in[6];
  const float* emb  = (const float*)d_in[7];
  const float* wfw  = (const float*)d_in[8];
  const float* wfb  = (const float*)d_in[9];
  float* out = (float*)d_out;

  char* ws = (char*)d_ws;
  size_t off = 0;
  auto alloc = [&](size_t b) { char* p = ws + off; off += (b + 255) & ~(size_t)255; return p; };

  unsigned short* wq16  = (unsigned short*)alloc((size_t)NE * NN * 2); // 256MB
  float*          h     = (float*)alloc((size_t)NN * NN * 4);          // 64MB
  unsigned short* x16   = (unsigned short*)alloc((size_t)NN * NN * 2); // 32MB
  unsigned short* w16   = (unsigned short*)alloc((size_t)NN * NN * 2); // 32MB
  unsigned short* h1b   = (unsigned short*)alloc((size_t)NN * NN * 2); // 32MB
  float* deg    = (float*)alloc(NN * 4);
  float* dis    = (float*)alloc(NN * 4);
  int*   cnt    = (int*)alloc(NN * 4);
  int*   cursor = (int*)alloc(NN * 4);
  int*   starts = (int*)alloc(NN * 4);
  int*   csr_e  = (int*)alloc(NE * 4);
  int*   csr_row= (int*)alloc(NE * 4);
  float* csr_nrm= (float*)alloc(NE * 4);
  float* P      = (float*)alloc((size_t)32 * NE * 4);                  // 4MB

  hipMemsetAsync(cnt, 0, NN * 4 * 2, stream);  // zero cnt + cursor

  k_deg_init<<<NN / 256, 256, 0, stream>>>(deg);
  k_edge_accum<<<NE / 256, 256, 0, stream>>>(ei, ew, deg, cnt);
  k_dis<<<NN / 256, 256, 0, stream>>>(deg, dis);
  k_scan<<<1, 1024, 0, stream>>>(cnt, starts);
  k_fill<<<NE / 256, 256, 0, stream>>>(ei, starts, cursor, csr_e);
  k_sortnorm<<<NN / 256, 256, 0, stream>>>(ei, ew, starts, cnt, dis, csr_e, csr_row, csr_nrm);

  k_f2bf<<<1024, 256, 0, stream>>>(x, x16, (long)NN * NN / 8);
  k_f2bf<<<1024, 256, 0, stream>>>(gcnw, w16, (long)NN * NN / 8);
  k_f2bf<<<2048, 256, 0, stream>>>(wqw, wq16, (long)NE * NN / 8);

  // h = x @ gcn_w.T   (M=N=K=4096): 16x16 blocks of 256x256
  gemm8<false><<<16 * 16, 512, 0, stream>>>(x16, w16, NN, NN, 16, h, nullptr, nullptr, nullptr);

  // aggregate + tanh -> H1 (bf16)
  k_agg<<<NN, 256, 0, stream>>>(h, dis, starts, cnt, csr_row, csr_nrm, gcnb, h1b);

  // fused: P[rb*2+wr][e] = sum_rows wf[row] * tanh(H1 @ wq_w.T + wq_b)
  gemm8<true><<<16 * 128, 512, 0, stream>>>(h1b, wq16, NE, NN, 16, nullptr, wqb, wfw, P);

  k_final<<<NE / 256, 256, 0, stream>>>(P, emb, wfw, wfb, out);
}

// Round 7
// 2981.706 us; speedup vs baseline: 1.0466x; 1.0466x over previous
//
#include <hip/hip_runtime.h>
#include <hip/hip_bf16.h>

#define NN 4096    // nodes == feature dim
#define NE 32768   // edges
#define NEMB 8

typedef __bf16 bf16x8 __attribute__((ext_vector_type(8)));
typedef float  f32x4  __attribute__((ext_vector_type(4)));

__device__ __forceinline__ unsigned short f2bf(float f) {
  union { float f; unsigned int u; } v; v.f = f;
  return (unsigned short)((v.u + 0x7FFFu + ((v.u >> 16) & 1u)) >> 16);
}

// ---------------- f32 -> bf16 bulk convert ----------------
__global__ void k_f2bf(const float* __restrict__ in, unsigned short* __restrict__ out, long n8) {
  long i = (long)blockIdx.x * blockDim.x + threadIdx.x;
  long stride = (long)gridDim.x * blockDim.x;
  for (long j = i; j < n8; j += stride) {
    const float* p = in + j * 8;
    float4 a = *(const float4*)p;
    float4 b = *(const float4*)(p + 4);
    union { unsigned short u[8]; uint4 v; } o;
    o.u[0] = f2bf(a.x); o.u[1] = f2bf(a.y); o.u[2] = f2bf(a.z); o.u[3] = f2bf(a.w);
    o.u[4] = f2bf(b.x); o.u[5] = f2bf(b.y); o.u[6] = f2bf(b.z); o.u[7] = f2bf(b.w);
    *(uint4*)(out + j * 8) = o.v;
  }
}

// ---------------- graph prep ----------------
__global__ void k_deg_init(float* deg) { deg[blockIdx.x * 256 + threadIdx.x] = 1.0f; }

__global__ void k_edge_accum(const int* __restrict__ ei, const float* __restrict__ ew,
                             float* deg, int* cnt) {
  int e = blockIdx.x * 256 + threadIdx.x;
  if (e >= NE) return;
  int c = ei[NE + e];
  atomicAdd(&deg[c], ew[e]);
  atomicAdd(&cnt[c], 1);
}

__global__ void k_dis(const float* __restrict__ deg, float* __restrict__ dis) {
  int i = blockIdx.x * 256 + threadIdx.x;
  float d = deg[i];
  dis[i] = d > 0.f ? rsqrtf(d) : 0.f;
}

__global__ void k_scan(const int* __restrict__ cnt, int* __restrict__ starts) {
  __shared__ int sh[1024];
  int tid = threadIdx.x;
  int base = tid * 4;
  int v[4]; int sum = 0;
  for (int i = 0; i < 4; i++) { v[i] = cnt[base + i]; sum += v[i]; }
  sh[tid] = sum;
  __syncthreads();
  for (int offd = 1; offd < 1024; offd <<= 1) {
    int t = (tid >= offd) ? sh[tid - offd] : 0;
    __syncthreads();
    sh[tid] += t;
    __syncthreads();
  }
  int run = sh[tid] - sum;
  for (int i = 0; i < 4; i++) { starts[base + i] = run; run += v[i]; }
}

__global__ void k_fill(const int* __restrict__ ei, const int* __restrict__ starts,
                       int* cursor, int* csr_e) {
  int e = blockIdx.x * 256 + threadIdx.x;
  if (e >= NE) return;
  int c = ei[NE + e];
  int pos = atomicAdd(&cursor[c], 1);
  csr_e[starts[c] + pos] = e;
}

__global__ void k_sortnorm(const int* __restrict__ ei, const float* __restrict__ ew,
                           const int* __restrict__ starts, const int* __restrict__ cnt,
                           const float* __restrict__ dis,
                           int* csr_e, int* __restrict__ csr_row, float* __restrict__ csr_nrm) {
  int n = blockIdx.x * 256 + threadIdx.x;
  if (n >= NN) return;
  int s = starts[n], c = cnt[n];
  for (int i = 1; i < c; i++) {
    int key = csr_e[s + i]; int j = i - 1;
    while (j >= 0 && csr_e[s + j] > key) { csr_e[s + j + 1] = csr_e[s + j]; j--; }
    csr_e[s + j + 1] = key;
  }
  float dn = dis[n];
  for (int i = 0; i < c; i++) {
    int e = csr_e[s + i];
    int r = ei[e];
    csr_row[s + i] = r;
    csr_nrm[s + i] = dis[r] * ew[e] * dn;
  }
}

// ---------------- aggregate + tanh -> H1 (bf16) ----------------
__global__ __launch_bounds__(256) void k_agg(
    const float* __restrict__ h, const float* __restrict__ dis,
    const int* __restrict__ starts, const int* __restrict__ cnt,
    const int* __restrict__ csr_row, const float* __restrict__ csr_nrm,
    const float* __restrict__ gcn_b, unsigned short* __restrict__ H1b) {
  int n = blockIdx.x;
  int tid = threadIdx.x;
  float dn = dis[n];
  float sw = dn * dn;
  float acc[16];
  const float* hn = h + (size_t)n * NN;
  #pragma unroll
  for (int i = 0; i < 16; i++) { int f = tid + i * 256; acc[i] = sw * hn[f] + gcn_b[f]; }
  int s = starts[n], c = cnt[n];
  __shared__ int   s_row[64];
  __shared__ float s_nrm[64];
  for (int base = 0; base < c; base += 64) {
    int m = min(64, c - base);
    __syncthreads();
    if (tid < m) { s_row[tid] = csr_row[s + base + tid]; s_nrm[tid] = csr_nrm[s + base + tid]; }
    __syncthreads();
    for (int j = 0; j < m; j++) {
      const float* hr = h + (size_t)s_row[j] * NN;
      float wgt = s_nrm[j];
      #pragma unroll
      for (int i = 0; i < 16; i++) acc[i] += wgt * hr[tid + i * 256];
    }
  }
  #pragma unroll
  for (int i = 0; i < 16; i++)
    H1b[(size_t)n * NN + tid + i * 256] = f2bf(tanhf(acc[i]));
}

// ------- 8-phase 256x256 GEMM, 4 waves (1/SIMD), 128x128/wave, reg-pipelined -------
__device__ __forceinline__ void gload16(const void* g, void* l) {
  __builtin_amdgcn_global_load_lds(
      (const __attribute__((address_space(1))) unsigned int*)g,
      (__attribute__((address_space(3))) unsigned int*)l, 16, 0, 0);
}

#define BARX() do { __builtin_amdgcn_sched_barrier(0); __builtin_amdgcn_s_barrier(); __builtin_amdgcn_sched_barrier(0); } while (0)
#define LGKM(n) do { asm volatile("s_waitcnt lgkmcnt(" #n ")" ::: "memory"); __builtin_amdgcn_sched_barrier(0); } while (0)
#define VMC(n) do { asm volatile("s_waitcnt vmcnt(" #n ")" ::: "memory"); } while (0)

// LDS: [buf][A/B][kk][frag 0..15][64 slots x 8 shorts] (16-B slots), 128 KiB.
// Producer: lane l = 4q+j stages M[frag*16+q][chunk j ^ ((q>>1)&3)] (64-B segments).
// Consumer: lane (r=l&15, c=l>>4) reads slot 4r + (c ^ ((r>>1)&3)) -> 0 conflicts.
// 4 waves: wave w stages frags w*4..w*4+3 (4 gload16 per STAGE).
// Reg pipeline: phase p's top issues p+1's fragments into the alternate set;
// LGKM(4|12) at p retires p-1's reads (landed under p-1's MFMA window).
// vmcnt ledger (4-load stages, VMC(12) at odd-phase ends): steady state keeps
// 3-4 stages in flight; each stage retires exactly one barrier before first read.

#define STAGE(buf, mat, kk, tk) do { \
    size_t off_ = (size_t)(tk) * 64 + (kk) * 32; \
    gload16((mat ? gB0 : gA0) + off_, &LDS[buf][mat][kk][c0][0]); \
    gload16((mat ? gB1 : gA1) + off_, &LDS[buf][mat][kk][c0 + 1][0]); \
    gload16((mat ? gB2 : gA2) + off_, &LDS[buf][mat][kk][c0 + 2][0]); \
    gload16((mat ? gB3 : gA3) + off_, &LDS[buf][mat][kk][c0 + 3][0]); \
  } while (0)

#define LDA4(dst, buf, kk, q) do { \
    const unsigned short* b_ = &LDS[buf][0][kk][wr * 8 + (q) * 4][0] + aoff; \
    dst[0] = *(const bf16x8*)(b_); \
    dst[1] = *(const bf16x8*)(b_ + 512); \
    dst[2] = *(const bf16x8*)(b_ + 1024); \
    dst[3] = *(const bf16x8*)(b_ + 1536); \
  } while (0)

#define LDB8(dst, buf, kk) do { \
    const unsigned short* b_ = &LDS[buf][1][kk][wc * 8][0] + aoff; \
    _Pragma("unroll") \
    for (int i_ = 0; i_ < 8; i_++) dst[i_] = *(const bf16x8*)(b_ + i_ * 512); \
  } while (0)

#define MMA32(q, av, bv) do { \
    __builtin_amdgcn_s_setprio(1); \
    _Pragma("unroll") \
    for (int mf_ = 0; mf_ < 4; mf_++) \
      _Pragma("unroll") \
      for (int nf_ = 0; nf_ < 8; nf_++) \
        acc[(q) * 4 + mf_][nf_] = __builtin_amdgcn_mfma_f32_16x16x32_bf16(av[mf_], bv[nf_], acc[(q) * 4 + mf_][nf_], 0, 0, 0); \
    __builtin_amdgcn_s_setprio(0); \
  } while (0)

template<bool FUSED>
__global__ __launch_bounds__(256, 1) void gemm4w(
    const unsigned short* __restrict__ A,  // [M][K] bf16
    const unsigned short* __restrict__ B,  // [N][K] bf16
    int N, int K, int nRb,
    float* __restrict__ outF,
    const float* __restrict__ colBias,
    const float* __restrict__ rowW,
    float* __restrict__ P) {
  __shared__ unsigned short LDS[2][2][2][16][512];  // 128 KiB

  const int nwg = gridDim.x, n8 = nwg >> 3;
  const int bid = blockIdx.x;
  const int swz = (bid & 7) * n8 + (bid >> 3);   // XCD-aware, bijective (nwg % 8 == 0)
  const int rb = swz % nRb, cb = swz / nRb;
  const int row0 = rb * 256, col0 = cb * 256;

  const int tid = threadIdx.x;
  const int w = tid >> 6, l = tid & 63;
  const int wr = w >> 1, wc = w & 1;             // 2M x 2N wave grid, 128x128/wave
  const int l15 = l & 15, kl = l >> 4;

  // producer gather: wave w owns frags c0..c0+3; lane l = 4q+j
  const int c0 = w * 4;
  const int pq = l >> 2;
  const int pc = (l & 3) ^ ((l >> 3) & 3);
  const unsigned short* gA0 = A + (size_t)(row0 + c0 * 16 + pq) * K + pc * 8;
  const unsigned short* gA1 = gA0 + (size_t)16 * K;
  const unsigned short* gA2 = gA0 + (size_t)32 * K;
  const unsigned short* gA3 = gA0 + (size_t)48 * K;
  const unsigned short* gB0 = B + (size_t)(col0 + c0 * 16 + pq) * K + pc * 8;
  const unsigned short* gB1 = gB0 + (size_t)16 * K;
  const unsigned short* gB2 = gB0 + (size_t)32 * K;
  const unsigned short* gB3 = gB0 + (size_t)48 * K;

  const int aoff = l15 * 32 + ((kl ^ ((l >> 1) & 3)) << 3);

  f32x4 acc[8][8];
  #pragma unroll
  for (int m = 0; m < 8; m++)
    #pragma unroll
    for (int n = 0; n < 8; n++)
      acc[m][n] = f32x4{0.f, 0.f, 0.f, 0.f};

  bf16x8 avA[4], avB[4], bvA[8], bvB[8];

  // prologue: tile0 fully + tile1 kk0; retire tile0; preload ph1 fragments
  STAGE(0, 0, 0, 0); STAGE(0, 1, 0, 0); STAGE(0, 0, 1, 0); STAGE(0, 1, 1, 0);
  STAGE(1, 0, 0, 1); STAGE(1, 1, 0, 1);
  VMC(8);
  BARX();
  LDB8(bvA, 0, 0); LDA4(avA, 0, 0, 0);

  const int NIT = K >> 7;   // 2 K-tiles (BK=64) per iteration
  for (int i = 0; i < NIT; i++) {
    const int ta = 2 * i, tb = 2 * i + 1;
    const bool mid = (i < NIT - 1);
    // ph1: MMA(b0,kk0,q0) | early av(b0,kk0,q1) | stage A-kk1(tb)
    LDA4(avB, 0, 0, 1);
    STAGE(1, 0, 1, tb);
    BARX(); LGKM(4); MMA32(0, avA, bvA); VMC(12); BARX();
    // ph2: MMA(b0,kk0,q1) | early bv+av(b0,kk1,q0) | stage B-kk1(tb)
    LDB8(bvB, 0, 1); LDA4(avA, 0, 1, 0);
    STAGE(1, 1, 1, tb);
    BARX(); LGKM(12); MMA32(1, avB, bvA); BARX();
    // ph3: MMA(b0,kk1,q0) | early av(b0,kk1,q1) | stage A-kk0(ta+2)
    LDA4(avB, 0, 1, 1);
    if (mid) STAGE(0, 0, 0, ta + 2);
    BARX(); LGKM(4); MMA32(0, avA, bvB);
    if (mid) VMC(12); else VMC(8);
    BARX();
    // ph4: MMA(b0,kk1,q1) | early bv+av(b1,kk0,q0) | stage B-kk0(ta+2)
    LDB8(bvA, 1, 0); LDA4(avA, 1, 0, 0);
    if (mid) STAGE(0, 1, 0, ta + 2);
    BARX(); LGKM(12); MMA32(1, avB, bvB); BARX();
    // ph5: MMA(b1,kk0,q0) | early av(b1,kk0,q1) | stage A-kk1(ta+2)
    LDA4(avB, 1, 0, 1);
    if (mid) STAGE(0, 0, 1, ta + 2);
    BARX(); LGKM(4); MMA32(0, avA, bvA);
    if (mid) VMC(12); else VMC(0);
    BARX();
    // ph6: MMA(b1,kk0,q1) | early bv+av(b1,kk1,q0) | stage B-kk1(ta+2)
    LDB8(bvB, 1, 1); LDA4(avA, 1, 1, 0);
    if (mid) STAGE(0, 1, 1, ta + 2);
    BARX(); LGKM(12); MMA32(1, avB, bvA); BARX();
    // ph7: MMA(b1,kk1,q0) | early av(b1,kk1,q1) | stage A-kk0(tb+2)
    LDA4(avB, 1, 1, 1);
    if (mid) STAGE(1, 0, 0, tb + 2);
    BARX(); LGKM(4); MMA32(0, avA, bvB);
    if (mid) VMC(12);
    BARX();
    // ph8: MMA(b1,kk1,q1) | early bv+av(next b0,kk0,q0) | stage B-kk0(tb+2)
    if (mid) {
      LDB8(bvA, 0, 0); LDA4(avA, 0, 0, 0);
      STAGE(1, 1, 0, tb + 2);
      BARX(); LGKM(12); MMA32(1, avB, bvB); BARX();
    } else {
      BARX(); LGKM(0); MMA32(1, avB, bvB); BARX();
    }
  }

  if (!FUSED) {
    #pragma unroll
    for (int mf = 0; mf < 8; mf++)
      #pragma unroll
      for (int nf = 0; nf < 8; nf++) {
        int row = row0 + wr * 128 + mf * 16 + kl * 4;
        int col = col0 + wc * 128 + nf * 16 + l15;
        float* o = outF + (size_t)row * N + col;
        #pragma unroll
        for (int r = 0; r < 4; r++) o[(size_t)r * N] = acc[mf][nf][r];
      }
  } else {
    #pragma unroll
    for (int nf = 0; nf < 8; nf++) {
      int col = col0 + wc * 128 + nf * 16 + l15;
      float bias = colBias[col];
      float s = 0.f;
      #pragma unroll
      for (int mf = 0; mf < 8; mf++) {
        int rbase = row0 + wr * 128 + mf * 16 + kl * 4;
        #pragma unroll
        for (int r = 0; r < 4; r++)
          s += rowW[rbase + r] * tanhf(acc[mf][nf][r] + bias);
      }
      s += __shfl_xor(s, 16, 64);
      s += __shfl_xor(s, 32, 64);
      if (l < 16) P[(size_t)(rb * 2 + wr) * N + col] = s;
    }
  }
}

// ---------------- final deterministic reduction ----------------
__global__ void k_final(const float* __restrict__ P, const float* __restrict__ emb,
                        const float* __restrict__ wf, const float* __restrict__ wfb,
                        float* __restrict__ out) {
  int e = blockIdx.x * 256 + threadIdx.x;
  float s = 0.f;
  for (int r = 0; r < 32; r++) s += P[(size_t)r * NE + e];
  float c = wfb[0];
  #pragma unroll
  for (int k = 0; k < NEMB; k++) c += emb[e * NEMB + k] * wf[NN + k];
  out[e] = s + c;
}

extern "C" void kernel_launch(void* const* d_in, const int* in_sizes, int n_in,
                              void* d_out, int out_size, void* d_ws, size_t ws_size,
                              hipStream_t stream) {
  const float* x    = (const float*)d_in[0];
  const int*   ei   = (const int*)d_in[1];
  const float* ew   = (const float*)d_in[2];
  const float* gcnw = (const float*)d_in[3];
  const float* gcnb = (const float*)d_in[4];
  const float* wqw  = (const float*)d_in[5];
  const float* wqb  = (const float*)d_in[6];
  const float* emb  = (const float*)d_in[7];
  const float* wfw  = (const float*)d_in[8];
  const float* wfb  = (const float*)d_in[9];
  float* out = (float*)d_out;

  char* ws = (char*)d_ws;
  size_t off = 0;
  auto alloc = [&](size_t b) { char* p = ws + off; off += (b + 255) & ~(size_t)255; return p; };

  unsigned short* wq16  = (unsigned short*)alloc((size_t)NE * NN * 2); // 256MB
  float*          h     = (float*)alloc((size_t)NN * NN * 4);          // 64MB
  unsigned short* x16   = (unsigned short*)alloc((size_t)NN * NN * 2); // 32MB
  unsigned short* w16   = (unsigned short*)alloc((size_t)NN * NN * 2); // 32MB
  unsigned short* h1b   = (unsigned short*)alloc((size_t)NN * NN * 2); // 32MB
  float* deg    = (float*)alloc(NN * 4);
  float* dis    = (float*)alloc(NN * 4);
  int*   cnt    = (int*)alloc(NN * 4);
  int*   cursor = (int*)alloc(NN * 4);
  int*   starts = (int*)alloc(NN * 4);
  int*   csr_e  = (int*)alloc(NE * 4);
  int*   csr_row= (int*)alloc(NE * 4);
  float* csr_nrm= (float*)alloc(NE * 4);
  float* P      = (float*)alloc((size_t)32 * NE * 4);                  // 4MB

  hipMemsetAsync(cnt, 0, NN * 4 * 2, stream);  // zero cnt + cursor

  k_deg_init<<<NN / 256, 256, 0, stream>>>(deg);
  k_edge_accum<<<NE / 256, 256, 0, stream>>>(ei, ew, deg, cnt);
  k_dis<<<NN / 256, 256, 0, stream>>>(deg, dis);
  k_scan<<<1, 1024, 0, stream>>>(cnt, starts);
  k_fill<<<NE / 256, 256, 0, stream>>>(ei, starts, cursor, csr_e);
  k_sortnorm<<<NN / 256, 256, 0, stream>>>(ei, ew, starts, cnt, dis, csr_e, csr_row, csr_nrm);

  k_f2bf<<<1024, 256, 0, stream>>>(x, x16, (long)NN * NN / 8);
  k_f2bf<<<1024, 256, 0, stream>>>(gcnw, w16, (long)NN * NN / 8);
  k_f2bf<<<2048, 256, 0, stream>>>(wqw, wq16, (long)NE * NN / 8);

  // h = x @ gcn_w.T   (M=N=K=4096): 16x16 blocks of 256x256
  gemm4w<false><<<16 * 16, 256, 0, stream>>>(x16, w16, NN, NN, 16, h, nullptr, nullptr, nullptr);

  // aggregate + tanh -> H1 (bf16)
  k_agg<<<NN, 256, 0, stream>>>(h, dis, starts, cnt, csr_row, csr_nrm, gcnb, h1b);

  // fused: P[rb*2+wr][e] = sum_rows wf[row] * tanh(H1 @ wq_w.T + wq_b)
  gemm4w<true><<<16 * 128, 256, 0, stream>>>(h1b, wq16, NE, NN, 16, nullptr, wqb, wfw, P);

  k_final<<<NE / 256, 256, 0, stream>>>(P, emb, wfw, wfb, out);
}

// Round 8
// 1416.499 us; speedup vs baseline: 2.2030x; 2.1050x over previous
//
#include <hip/hip_runtime.h>
#include <hip/hip_bf16.h>

#define NN 4096    // nodes == feature dim
#define NE 32768   // edges
#define NEMB 8

typedef __bf16 bf16x8 __attribute__((ext_vector_type(8)));
typedef float  f32x4  __attribute__((ext_vector_type(4)));

__device__ __forceinline__ unsigned short f2bf(float f) {
  union { float f; unsigned int u; } v; v.f = f;
  return (unsigned short)((v.u + 0x7FFFu + ((v.u >> 16) & 1u)) >> 16);
}

// ---------------- f32 -> bf16 bulk convert ----------------
__global__ void k_f2bf(const float* __restrict__ in, unsigned short* __restrict__ out, long n8) {
  long i = (long)blockIdx.x * blockDim.x + threadIdx.x;
  long stride = (long)gridDim.x * blockDim.x;
  for (long j = i; j < n8; j += stride) {
    const float* p = in + j * 8;
    float4 a = *(const float4*)p;
    float4 b = *(const float4*)(p + 4);
    union { unsigned short u[8]; uint4 v; } o;
    o.u[0] = f2bf(a.x); o.u[1] = f2bf(a.y); o.u[2] = f2bf(a.z); o.u[3] = f2bf(a.w);
    o.u[4] = f2bf(b.x); o.u[5] = f2bf(b.y); o.u[6] = f2bf(b.z); o.u[7] = f2bf(b.w);
    *(uint4*)(out + j * 8) = o.v;
  }
}

// ---------------- graph prep ----------------
__global__ void k_deg_init(float* deg) { deg[blockIdx.x * 256 + threadIdx.x] = 1.0f; }

__global__ void k_edge_accum(const int* __restrict__ ei, const float* __restrict__ ew,
                             float* deg, int* cnt) {
  int e = blockIdx.x * 256 + threadIdx.x;
  if (e >= NE) return;
  int c = ei[NE + e];
  atomicAdd(&deg[c], ew[e]);
  atomicAdd(&cnt[c], 1);
}

__global__ void k_dis(const float* __restrict__ deg, float* __restrict__ dis) {
  int i = blockIdx.x * 256 + threadIdx.x;
  float d = deg[i];
  dis[i] = d > 0.f ? rsqrtf(d) : 0.f;
}

__global__ void k_scan(const int* __restrict__ cnt, int* __restrict__ starts) {
  __shared__ int sh[1024];
  int tid = threadIdx.x;
  int base = tid * 4;
  int v[4]; int sum = 0;
  for (int i = 0; i < 4; i++) { v[i] = cnt[base + i]; sum += v[i]; }
  sh[tid] = sum;
  __syncthreads();
  for (int offd = 1; offd < 1024; offd <<= 1) {
    int t = (tid >= offd) ? sh[tid - offd] : 0;
    __syncthreads();
    sh[tid] += t;
    __syncthreads();
  }
  int run = sh[tid] - sum;
  for (int i = 0; i < 4; i++) { starts[base + i] = run; run += v[i]; }
}

__global__ void k_fill(const int* __restrict__ ei, const int* __restrict__ starts,
                       int* cursor, int* csr_e) {
  int e = blockIdx.x * 256 + threadIdx.x;
  if (e >= NE) return;
  int c = ei[NE + e];
  int pos = atomicAdd(&cursor[c], 1);
  csr_e[starts[c] + pos] = e;
}

__global__ void k_sortnorm(const int* __restrict__ ei, const float* __restrict__ ew,
                           const int* __restrict__ starts, const int* __restrict__ cnt,
                           const float* __restrict__ dis,
                           int* csr_e, int* __restrict__ csr_row, float* __restrict__ csr_nrm) {
  int n = blockIdx.x * 256 + threadIdx.x;
  if (n >= NN) return;
  int s = starts[n], c = cnt[n];
  for (int i = 1; i < c; i++) {
    int key = csr_e[s + i]; int j = i - 1;
    while (j >= 0 && csr_e[s + j] > key) { csr_e[s + j + 1] = csr_e[s + j]; j--; }
    csr_e[s + j + 1] = key;
  }
  float dn = dis[n];
  for (int i = 0; i < c; i++) {
    int e = csr_e[s + i];
    int r = ei[e];
    csr_row[s + i] = r;
    csr_nrm[s + i] = dis[r] * ew[e] * dn;
  }
}

// ---------------- aggregate + tanh -> H1 (bf16) ----------------
__global__ __launch_bounds__(256) void k_agg(
    const float* __restrict__ h, const float* __restrict__ dis,
    const int* __restrict__ starts, const int* __restrict__ cnt,
    const int* __restrict__ csr_row, const float* __restrict__ csr_nrm,
    const float* __restrict__ gcn_b, unsigned short* __restrict__ H1b) {
  int n = blockIdx.x;
  int tid = threadIdx.x;
  float dn = dis[n];
  float sw = dn * dn;
  float acc[16];
  const float* hn = h + (size_t)n * NN;
  #pragma unroll
  for (int i = 0; i < 16; i++) { int f = tid + i * 256; acc[i] = sw * hn[f] + gcn_b[f]; }
  int s = starts[n], c = cnt[n];
  __shared__ int   s_row[64];
  __shared__ float s_nrm[64];
  for (int base = 0; base < c; base += 64) {
    int m = min(64, c - base);
    __syncthreads();
    if (tid < m) { s_row[tid] = csr_row[s + base + tid]; s_nrm[tid] = csr_nrm[s + base + tid]; }
    __syncthreads();
    for (int j = 0; j < m; j++) {
      const float* hr = h + (size_t)s_row[j] * NN;
      float wgt = s_nrm[j];
      #pragma unroll
      for (int i = 0; i < 16; i++) acc[i] += wgt * hr[tid + i * 256];
    }
  }
  #pragma unroll
  for (int i = 0; i < 16; i++)
    H1b[(size_t)n * NN + tid + i * 256] = f2bf(tanhf(acc[i]));
}

// -------- 8-phase 256x256 MFMA GEMM, 1 barrier/phase, compiler-counted lgkm --------
__device__ __forceinline__ void gload16(const void* g, void* l) {
  __builtin_amdgcn_global_load_lds(
      (const __attribute__((address_space(1))) unsigned int*)g,
      (__attribute__((address_space(3))) unsigned int*)l, 16, 0, 0);
}

#define BARX() do { __builtin_amdgcn_sched_barrier(0); __builtin_amdgcn_s_barrier(); __builtin_amdgcn_sched_barrier(0); } while (0)
#define VMC(n) do { asm volatile("s_waitcnt vmcnt(" #n ")" ::: "memory"); } while (0)

// LDS: [buf][A/B][kk][frag 0..15][64 slots x 8 shorts] (16-B slots).
// Producer (gload_lds, linear dest): lane l = 4q+j stages
//   M[frag*16 + q][k-chunk j ^ ((q>>1)&3)]  -> quad = same row, 64-B segment (coalesced).
// Consumer: lane λ (row r=λ&15, chunk c=λ>>4) reads slot 4r + (c ^ ((r>>1)&3)).
// Every 8-lane group hits slots ≡ {0,4,1,5,2,6,3,7} mod 8 -> zero bank conflicts.
//
// SCHEDULE: ONE barrier per phase. Phase = {ds_reads; STAGE issue; MFMA cluster
// (compiler inserts counted lgkmcnt so early MFMAs overlap later reads); VMC; BARX}.
// WAR safety: every read has an in-cluster consumer, DS retirement is FIFO, so all
// of a wave's reads retire before its last MFMA issues -> before it crosses BARX;
// the overwriting STAGE is issued only after that barrier.
// RAW safety (stage s -> consumer c, own-wave VMC retires s before a barrier < c):
//   ph1,2 (buf1 kk1)  -> retired VMC(8)@ph6 -> read ph7      (4-phase cover)
//   ph3,4 (buf0 kk0') -> retired VMC(8)@ph8 -> read next ph1
//   ph5,6 (buf0 kk1') -> retired VMC(8)@nph2 -> read next ph3
//   ph7,8 (buf1 kk0') -> retired VMC(8)@nph4 -> read next ph5
// Steady state: 8 loads outstanding at every even-phase end (verified periodic).
// Last iter (no ph3..ph8 stages): VMC 8@ph2, 4@ph4, 0@ph6.

#define STAGE(buf, mat, kk, tk) do { \
    size_t off_ = (size_t)(tk) * 64 + (kk) * 32; \
    gload16((mat ? gB0 : gA0) + off_, &LDS[buf][mat][kk][c0][0]); \
    gload16((mat ? gB1 : gA1) + off_, &LDS[buf][mat][kk][c0 + 1][0]); \
  } while (0)

#define LDA4(dst, buf, kk, q) do { \
    const unsigned short* b_ = &LDS[buf][0][kk][wr * 8 + (q) * 4][0] + aoff; \
    dst[0] = *(const bf16x8*)(b_); \
    dst[1] = *(const bf16x8*)(b_ + 512); \
    dst[2] = *(const bf16x8*)(b_ + 1024); \
    dst[3] = *(const bf16x8*)(b_ + 1536); \
  } while (0)

#define LDB4(dst, buf, kk) do { \
    const unsigned short* b_ = &LDS[buf][1][kk][wc * 4][0] + aoff; \
    dst[0] = *(const bf16x8*)(b_); \
    dst[1] = *(const bf16x8*)(b_ + 512); \
    dst[2] = *(const bf16x8*)(b_ + 1024); \
    dst[3] = *(const bf16x8*)(b_ + 1536); \
  } while (0)

#define MMA16(q, av, bv) do { \
    __builtin_amdgcn_s_setprio(1); \
    _Pragma("unroll") \
    for (int mf_ = 0; mf_ < 4; mf_++) \
      _Pragma("unroll") \
      for (int nf_ = 0; nf_ < 4; nf_++) \
        acc[(q) * 4 + mf_][nf_] = __builtin_amdgcn_mfma_f32_16x16x32_bf16(av[mf_], bv[nf_], acc[(q) * 4 + mf_][nf_], 0, 0, 0); \
    __builtin_amdgcn_s_setprio(0); \
  } while (0)

template<bool FUSED>
__global__ __launch_bounds__(512, 2) void gemm8(
    const unsigned short* __restrict__ A,  // [M][K] bf16
    const unsigned short* __restrict__ B,  // [N][K] bf16
    int N, int K, int nRb,
    float* __restrict__ outF,
    const float* __restrict__ colBias,
    const float* __restrict__ rowW,
    float* __restrict__ P) {
  __shared__ unsigned short LDS[2][2][2][16][512];  // 128 KiB

  const int nwg = gridDim.x, n8 = nwg >> 3;
  const int bid = blockIdx.x;
  const int swz = (bid & 7) * n8 + (bid >> 3);   // XCD-aware, bijective (nwg % 8 == 0)
  const int rb = swz % nRb, cb = swz / nRb;
  const int row0 = rb * 256, col0 = cb * 256;

  const int tid = threadIdx.x;
  const int w = tid >> 6, l = tid & 63;
  const int wr = w >> 2, wc = w & 3;             // 2M x 4N wave grid
  const int l15 = l & 15, kl = l >> 4;

  // producer gather: wave w owns frags c0, c0+1; lane l = 4q+j
  const int c0 = w * 2;
  const int pq = l >> 2;                          // row within 16-row frag
  const int pc = (l & 3) ^ ((l >> 3) & 3);        // XOR-permuted k-chunk (16 B units)
  const unsigned short* gA0 = A + (size_t)(row0 + c0 * 16 + pq) * K + pc * 8;
  const unsigned short* gA1 = gA0 + (size_t)16 * K;
  const unsigned short* gB0 = B + (size_t)(col0 + c0 * 16 + pq) * K + pc * 8;
  const unsigned short* gB1 = gB0 + (size_t)16 * K;

  // consumer read offset within a frag block (shorts): slot 4r + (c ^ ((r>>1)&3))
  const int aoff = l15 * 32 + ((kl ^ ((l >> 1) & 3)) << 3);

  f32x4 acc[8][4];
  #pragma unroll
  for (int m = 0; m < 8; m++)
    #pragma unroll
    for (int n = 0; n < 4; n++)
      acc[m][n] = f32x4{0.f, 0.f, 0.f, 0.f};

  // prologue: tile0 fully + tile1 kk0; retire tile0; publish
  STAGE(0, 0, 0, 0); STAGE(0, 1, 0, 0); STAGE(0, 0, 1, 0); STAGE(0, 1, 1, 0);
  STAGE(1, 0, 0, 1); STAGE(1, 1, 0, 1);
  VMC(4);
  BARX();

  const int NIT = K >> 7;   // 2 K-tiles (BK=64) per iteration
  for (int i = 0; i < NIT; i++) {
    const int ta = 2 * i, tb = 2 * i + 1;
    const bool mid = (i < NIT - 1);
    bf16x8 av[4], bv[4];
    // ph1: reads(buf0,kk0: B + A.q0) | stage A-kk1(tb) | MMA q0
    LDB4(bv, 0, 0); LDA4(av, 0, 0, 0);
    STAGE(1, 0, 1, tb);
    MMA16(0, av, bv);
    BARX();
    // ph2: reads(buf0,kk0: A.q1) | stage B-kk1(tb) | MMA q1 | VMC(8)
    LDA4(av, 0, 0, 1);
    STAGE(1, 1, 1, tb);
    MMA16(1, av, bv);
    VMC(8);
    BARX();
    // ph3: reads(buf0,kk1: B + A.q0) | stage A-kk0(ta+2) | MMA q0
    LDB4(bv, 0, 1); LDA4(av, 0, 1, 0);
    if (mid) STAGE(0, 0, 0, ta + 2);
    MMA16(0, av, bv);
    BARX();
    // ph4: reads(buf0,kk1: A.q1) | stage B-kk0(ta+2) | MMA q1 | VMC(8|4)
    LDA4(av, 0, 1, 1);
    if (mid) STAGE(0, 1, 0, ta + 2);
    MMA16(1, av, bv);
    if (mid) VMC(8); else VMC(4);
    BARX();
    // ph5: reads(buf1,kk0: B + A.q0) | stage A-kk1(ta+2) | MMA q0
    LDB4(bv, 1, 0); LDA4(av, 1, 0, 0);
    if (mid) STAGE(0, 0, 1, ta + 2);
    MMA16(0, av, bv);
    BARX();
    // ph6: reads(buf1,kk0: A.q1) | stage B-kk1(ta+2) | MMA q1 | VMC(8|0)
    LDA4(av, 1, 0, 1);
    if (mid) STAGE(0, 1, 1, ta + 2);
    MMA16(1, av, bv);
    if (mid) VMC(8); else VMC(0);
    BARX();
    // ph7: reads(buf1,kk1: B + A.q0) | stage A-kk0(tb+2) | MMA q0
    LDB4(bv, 1, 1); LDA4(av, 1, 1, 0);
    if (mid) STAGE(1, 0, 0, tb + 2);
    MMA16(0, av, bv);
    BARX();
    // ph8: reads(buf1,kk1: A.q1) | stage B-kk0(tb+2) | MMA q1 | VMC(8)
    LDA4(av, 1, 1, 1);
    if (mid) STAGE(1, 1, 0, tb + 2);
    MMA16(1, av, bv);
    if (mid) VMC(8);
    BARX();
  }

  if (!FUSED) {
    #pragma unroll
    for (int mf = 0; mf < 8; mf++)
      #pragma unroll
      for (int nf = 0; nf < 4; nf++) {
        int row = row0 + wr * 128 + mf * 16 + kl * 4;
        int col = col0 + wc * 64 + nf * 16 + l15;
        float* o = outF + (size_t)row * N + col;
        #pragma unroll
        for (int r = 0; r < 4; r++) o[(size_t)r * N] = acc[mf][nf][r];
      }
  } else {
    #pragma unroll
    for (int nf = 0; nf < 4; nf++) {
      int col = col0 + wc * 64 + nf * 16 + l15;
      float bias = colBias[col];
      float s = 0.f;
      #pragma unroll
      for (int mf = 0; mf < 8; mf++) {
        int rbase = row0 + wr * 128 + mf * 16 + kl * 4;
        #pragma unroll
        for (int r = 0; r < 4; r++)
          s += rowW[rbase + r] * tanhf(acc[mf][nf][r] + bias);
      }
      s += __shfl_xor(s, 16, 64);
      s += __shfl_xor(s, 32, 64);
      if (l < 16) P[(size_t)(rb * 2 + wr) * N + col] = s;
    }
  }
}

// ---------------- final deterministic reduction ----------------
__global__ void k_final(const float* __restrict__ P, const float* __restrict__ emb,
                        const float* __restrict__ wf, const float* __restrict__ wfb,
                        float* __restrict__ out) {
  int e = blockIdx.x * 256 + threadIdx.x;
  float s = 0.f;
  for (int r = 0; r < 32; r++) s += P[(size_t)r * NE + e];
  float c = wfb[0];
  #pragma unroll
  for (int k = 0; k < NEMB; k++) c += emb[e * NEMB + k] * wf[NN + k];
  out[e] = s + c;
}

extern "C" void kernel_launch(void* const* d_in, const int* in_sizes, int n_in,
                              void* d_out, int out_size, void* d_ws, size_t ws_size,
                              hipStream_t stream) {
  const float* x    = (const float*)d_in[0];
  const int*   ei   = (const int*)d_in[1];
  const float* ew   = (const float*)d_in[2];
  const float* gcnw = (const float*)d_in[3];
  const float* gcnb = (const float*)d_in[4];
  const float* wqw  = (const float*)d_in[5];
  const float* wqb  = (const float*)d_in[6];
  const float* emb  = (const float*)d_in[7];
  const float* wfw  = (const float*)d_in[8];
  const float* wfb  = (const float*)d_in[9];
  float* out = (float*)d_out;

  char* ws = (char*)d_ws;
  size_t off = 0;
  auto alloc = [&](size_t b) { char* p = ws + off; off += (b + 255) & ~(size_t)255; return p; };

  unsigned short* wq16  = (unsigned short*)alloc((size_t)NE * NN * 2); // 256MB
  float*          h     = (float*)alloc((size_t)NN * NN * 4);          // 64MB
  unsigned short* x16   = (unsigned short*)alloc((size_t)NN * NN * 2); // 32MB
  unsigned short* w16   = (unsigned short*)alloc((size_t)NN * NN * 2); // 32MB
  unsigned short* h1b   = (unsigned short*)alloc((size_t)NN * NN * 2); // 32MB
  float* deg    = (float*)alloc(NN * 4);
  float* dis    = (float*)alloc(NN * 4);
  int*   cnt    = (int*)alloc(NN * 4);
  int*   cursor = (int*)alloc(NN * 4);
  int*   starts = (int*)alloc(NN * 4);
  int*   csr_e  = (int*)alloc(NE * 4);
  int*   csr_row= (int*)alloc(NE * 4);
  float* csr_nrm= (float*)alloc(NE * 4);
  float* P      = (float*)alloc((size_t)32 * NE * 4);                  // 4MB

  hipMemsetAsync(cnt, 0, NN * 4 * 2, stream);  // zero cnt + cursor

  k_deg_init<<<NN / 256, 256, 0, stream>>>(deg);
  k_edge_accum<<<NE / 256, 256, 0, stream>>>(ei, ew, deg, cnt);
  k_dis<<<NN / 256, 256, 0, stream>>>(deg, dis);
  k_scan<<<1, 1024, 0, stream>>>(cnt, starts);
  k_fill<<<NE / 256, 256, 0, stream>>>(ei, starts, cursor, csr_e);
  k_sortnorm<<<NN / 256, 256, 0, stream>>>(ei, ew, starts, cnt, dis, csr_e, csr_row, csr_nrm);

  k_f2bf<<<1024, 256, 0, stream>>>(x, x16, (long)NN * NN / 8);
  k_f2bf<<<1024, 256, 0, stream>>>(gcnw, w16, (long)NN * NN / 8);
  k_f2bf<<<2048, 256, 0, stream>>>(wqw, wq16, (long)NE * NN / 8);

  // h = x @ gcn_w.T   (M=N=K=4096): 16x16 blocks of 256x256
  gemm8<false><<<16 * 16, 512, 0, stream>>>(x16, w16, NN, NN, 16, h, nullptr, nullptr, nullptr);

  // aggregate + tanh -> H1 (bf16)
  k_agg<<<NN, 256, 0, stream>>>(h, dis, starts, cnt, csr_row, csr_nrm, gcnb, h1b);

  // fused: P[rb*2+wr][e] = sum_rows wf[row] * tanh(H1 @ wq_w.T + wq_b)
  gemm8<true><<<16 * 128, 512, 0, stream>>>(h1b, wq16, NE, NN, 16, nullptr, wqb, wfw, P);

  k_final<<<NE / 256, 256, 0, stream>>>(P, emb, wfw, wfb, out);
}